// Round 1
// baseline (61.508 us; speedup 1.0000x reference)
//
#include <hip/hip_runtime.h>
#include <math.h>

// ---------------------------------------------------------------------------
// HybridQuantumLinear: enc = tanh(x @ W_in^T) * pi  -> 8-qubit circuit -> <Z_q>
//                      out = z @ W_out^T
// One wave (64 lanes) per batch element; 4 complex amplitudes per lane.
// Amplitude index i = lane*4 + k  (k = i & 3).  Qubit q lives at bit (7-q).
//   bits 0,1  -> in-lane (k bits)        (qubits 7, 6)
//   bits 2..7 -> lane bits 0..5          (qubits 5..0), shfl_xor masks 1..32
// theta is batch-invariant: pre-kernel computes cos/sin of theta/2 into d_ws.
// ---------------------------------------------------------------------------

__global__ void gate_table_kernel(const float* __restrict__ theta,
                                  float* __restrict__ tbl) {
  int t = blockIdx.x * blockDim.x + threadIdx.x;
  if (t < 96) {  // 4 layers * 8 qubits * 3 rots
    float h = 0.5f * theta[t];
    tbl[2 * t]     = cosf(h);
    tbl[2 * t + 1] = sinf(h);
  }
}

__device__ __forceinline__ float2 shfl_xor_f2(float2 v, int m) {
  float2 r;
  r.x = __shfl_xor(v.x, m, 64);
  r.y = __shfl_xor(v.y, m, 64);
  return r;
}

// --- in-lane 2x2 pair gates (old values of both amps needed) ----------------
__device__ __forceinline__ void rx_pair(float2& a0, float2& a1, float c, float s) {
  // g = [[c, -is], [-is, c]]
  float2 n0, n1;
  n0.x = fmaf(c, a0.x,  s * a1.y);
  n0.y = fmaf(c, a0.y, -s * a1.x);
  n1.x = fmaf(c, a1.x,  s * a0.y);
  n1.y = fmaf(c, a1.y, -s * a0.x);
  a0 = n0; a1 = n1;
}
__device__ __forceinline__ void ry_pair(float2& a0, float2& a1, float c, float s) {
  // g = [[c, -s], [s, c]]  (real)
  float2 n0, n1;
  n0.x = fmaf(c, a0.x, -s * a1.x);
  n0.y = fmaf(c, a0.y, -s * a1.y);
  n1.x = fmaf(s, a0.x,  c * a1.x);
  n1.y = fmaf(s, a0.y,  c * a1.y);
  a0 = n0; a1 = n1;
}
__device__ __forceinline__ void rz_amp(float2& a, float c, float sg) {
  // multiply by (c + i*sg); sg = bit ? +s : -s
  float2 n;
  n.x = fmaf(c, a.x, -sg * a.y);
  n.y = fmaf(c, a.y,  sg * a.x);
  a = n;
}

__device__ __forceinline__ void apply_rx(float2 (&a)[4], int q, float c, float s, int lane) {
  if (q == 7) {              // bit 0: pairs (0,1),(2,3)
    rx_pair(a[0], a[1], c, s);
    rx_pair(a[2], a[3], c, s);
  } else if (q == 6) {       // bit 1: pairs (0,2),(1,3)
    rx_pair(a[0], a[2], c, s);
    rx_pair(a[1], a[3], c, s);
  } else {                   // cross-lane; RX off-diagonal is symmetric (-is)
    int m = 1 << (5 - q);
    #pragma unroll
    for (int k = 0; k < 4; ++k) {
      float2 p = shfl_xor_f2(a[k], m);
      float2 n;
      n.x = fmaf(c, a[k].x,  s * p.y);
      n.y = fmaf(c, a[k].y, -s * p.x);
      a[k] = n;
    }
  }
}

__device__ __forceinline__ void apply_ry(float2 (&a)[4], int q, float c, float s, int lane) {
  if (q == 7) {
    ry_pair(a[0], a[1], c, s);
    ry_pair(a[2], a[3], c, s);
  } else if (q == 6) {
    ry_pair(a[0], a[2], c, s);
    ry_pair(a[1], a[3], c, s);
  } else {
    int m = 1 << (5 - q);
    float sgn = ((lane >> (5 - q)) & 1) ? s : -s;  // bit0: c*a - s*p ; bit1: c*a + s*p
    #pragma unroll
    for (int k = 0; k < 4; ++k) {
      float2 p = shfl_xor_f2(a[k], m);
      float2 n;
      n.x = fmaf(c, a[k].x, sgn * p.x);
      n.y = fmaf(c, a[k].y, sgn * p.y);
      a[k] = n;
    }
  }
}

__device__ __forceinline__ void apply_rz(float2 (&a)[4], int q, float c, float s, int lane) {
  if (q == 7) {              // sign from k bit 0
    rz_amp(a[0], c, -s); rz_amp(a[1], c,  s);
    rz_amp(a[2], c, -s); rz_amp(a[3], c,  s);
  } else if (q == 6) {       // sign from k bit 1
    rz_amp(a[0], c, -s); rz_amp(a[1], c, -s);
    rz_amp(a[2], c,  s); rz_amp(a[3], c,  s);
  } else {
    float sg = ((lane >> (5 - q)) & 1) ? s : -s;
    #pragma unroll
    for (int k = 0; k < 4; ++k) rz_amp(a[k], c, sg);
  }
}

// CNOT(control q, target q+1): control bit 7-q, target bit 6-q.
__device__ __forceinline__ void apply_cnot(float2 (&a)[4], int q, int lane) {
  if (q <= 4) {              // both bits are lane bits
    int m = 1 << (4 - q);    // target lane-bit mask
    bool ctrl = (lane >> (5 - q)) & 1;
    #pragma unroll
    for (int k = 0; k < 4; ++k) {
      float2 p = shfl_xor_f2(a[k], m);
      a[k].x = ctrl ? p.x : a[k].x;
      a[k].y = ctrl ? p.y : a[k].y;
    }
  } else if (q == 5) {       // control = lane bit 0, target = k bit 1
    bool ct = lane & 1;
    float2 n0 = ct ? a[2] : a[0];
    float2 n1 = ct ? a[3] : a[1];
    float2 n2 = ct ? a[0] : a[2];
    float2 n3 = ct ? a[1] : a[3];
    a[0] = n0; a[1] = n1; a[2] = n2; a[3] = n3;
  } else {                   // q == 6: control = k bit 1, target = k bit 0
    float2 t = a[2]; a[2] = a[3]; a[3] = t;
  }
}

__global__ __launch_bounds__(256) void hql_kernel(
    const float* __restrict__ x, const float* __restrict__ W_in,
    const float* __restrict__ W_out, const float* __restrict__ tbl,
    float* __restrict__ out, int B) {
  const int lane = threadIdx.x & 63;
  const int b = blockIdx.x * 4 + (threadIdx.x >> 6);
  if (b >= B) return;

  // ---- encoding GEMM: enc[q] = tanh(dot(x[b,:], W_in[q,:])) * pi ----------
  float xv[8];
  #pragma unroll
  for (int j = 0; j < 8; ++j) xv[j] = x[b * 512 + j * 64 + lane];

  float acc[8];
  #pragma unroll
  for (int q = 0; q < 8; ++q) {
    float s = 0.f;
    #pragma unroll
    for (int j = 0; j < 8; ++j) s = fmaf(xv[j], W_in[q * 512 + j * 64 + lane], s);
    acc[q] = s;
  }
  #pragma unroll
  for (int m = 1; m < 64; m <<= 1) {
    #pragma unroll
    for (int q = 0; q < 8; ++q) acc[q] += __shfl_xor(acc[q], m, 64);
  }

  float cq[8], sq[8];
  #pragma unroll
  for (int q = 0; q < 8; ++q) {
    float e  = __expf(2.f * acc[q]);
    float th = 1.f - __fdividef(2.f, e + 1.f);     // tanh
    float h  = 0.5f * 3.14159265358979323846f * th;
    cq[q] = __cosf(h);
    sq[q] = __sinf(h);
  }

  // ---- initial product state (all real) ------------------------------------
  float base = 1.f;
  #pragma unroll
  for (int q = 0; q < 6; ++q)
    base *= ((lane >> (5 - q)) & 1) ? sq[q] : cq[q];

  float2 a[4];
  a[0] = make_float2(base * cq[6] * cq[7], 0.f);
  a[1] = make_float2(base * cq[6] * sq[7], 0.f);
  a[2] = make_float2(base * sq[6] * cq[7], 0.f);
  a[3] = make_float2(base * sq[6] * sq[7], 0.f);

  // ---- PCE ansatz: 4 layers of (RX,RY,RZ) per qubit + brickwall CNOTs ------
  #pragma unroll
  for (int l = 0; l < 4; ++l) {
    #pragma unroll
    for (int q = 0; q < 8; ++q) {
      const int g = (l * 8 + q) * 3;   // gate base index (l*24 + q*3)
      apply_rx(a, q, tbl[2 * g + 0], tbl[2 * g + 1], lane);
      apply_ry(a, q, tbl[2 * g + 2], tbl[2 * g + 3], lane);
      apply_rz(a, q, tbl[2 * g + 4], tbl[2 * g + 5], lane);
    }
    #pragma unroll
    for (int i = (l & 1); i < 7; i += 2) apply_cnot(a, i, lane);
  }

  // ---- expvals <Z_q> --------------------------------------------------------
  float p0 = fmaf(a[0].x, a[0].x, a[0].y * a[0].y);
  float p1 = fmaf(a[1].x, a[1].x, a[1].y * a[1].y);
  float p2 = fmaf(a[2].x, a[2].x, a[2].y * a[2].y);
  float p3 = fmaf(a[3].x, a[3].x, a[3].y * a[3].y);
  float psum = (p0 + p1) + (p2 + p3);

  float z[8];
  #pragma unroll
  for (int q = 0; q < 6; ++q)
    z[q] = ((lane >> (5 - q)) & 1) ? -psum : psum;
  z[6] = (p0 + p1) - (p2 + p3);
  z[7] = (p0 - p1) + (p2 - p3);

  #pragma unroll
  for (int m = 1; m < 64; m <<= 1) {
    #pragma unroll
    for (int q = 0; q < 8; ++q) z[q] += __shfl_xor(z[q], m, 64);
  }

  // ---- output GEMM: out[b,o] = sum_q z[q] * W_out[o,q] ----------------------
  #pragma unroll
  for (int j = 0; j < 8; ++j) {
    int o = j * 64 + lane;
    float4 w0 = *(const float4*)(&W_out[o * 8]);
    float4 w1 = *(const float4*)(&W_out[o * 8 + 4]);
    float r = w0.x * z[0] + w0.y * z[1] + w0.z * z[2] + w0.w * z[3] +
              w1.x * z[4] + w1.y * z[5] + w1.z * z[6] + w1.w * z[7];
    out[b * 512 + o] = r;
  }
}

extern "C" void kernel_launch(void* const* d_in, const int* in_sizes, int n_in,
                              void* d_out, int out_size, void* d_ws, size_t ws_size,
                              hipStream_t stream) {
  const float* x     = (const float*)d_in[0];  // (B, 512)
  const float* W_in  = (const float*)d_in[1];  // (8, 512)
  const float* W_out = (const float*)d_in[2];  // (512, 8)
  const float* theta = (const float*)d_in[3];  // (4, 8, 3)
  float* out = (float*)d_out;
  float* tbl = (float*)d_ws;                   // 192 floats: cos/sin per gate

  const int B = in_sizes[0] / 512;             // 8192
  hipLaunchKernelGGL(gate_table_kernel, dim3(1), dim3(128), 0, stream, theta, tbl);
  hipLaunchKernelGGL(hql_kernel, dim3((B + 3) / 4), dim3(256), 0, stream,
                     x, W_in, W_out, tbl, out, B);
}

// Round 2
// 35.279 us; speedup vs baseline: 1.7435x; 1.7435x over previous
//
#include <hip/hip_runtime.h>
#include <hip/hip_bf16.h>
#include <math.h>

// ---------------------------------------------------------------------------
// HybridQuantumLinear via fixed-unitary GEMM.
//   enc = tanh(x@W_in^T)*pi ; psi_in[b] = prod-state (REAL, 256) ; psi_out =
//   U_fixed * psi_in (bf16 MFMA, K=256, N=512 re/im) ; z_q = sum sign*|psi|^2 ;
//   out = z @ W_out^T.
// k01: blocks 0..63 build U (one wave per basis column, fused RXRYRZ gates);
//      blocks 64.. compute enc + psi_in (one wave per batch row).
// k2:  256 blocks x 4 waves; block = 32 batch rows, wave = 32x128 output cols.
// Amp index i: bit(7-q) = qubit q. i = lane*4 + k  (lane bits 5..0 = qubits
// 0..5, k bit1 = qubit 6, k bit0 = qubit 7).
// ---------------------------------------------------------------------------

typedef __attribute__((ext_vector_type(8))) short bf16x8;
typedef __attribute__((ext_vector_type(4))) float f32x4;

__device__ __forceinline__ float2 shfl_xor_f2(float2 v, int m) {
  float2 r;
  r.x = __shfl_xor(v.x, m, 64);
  r.y = __shfl_xor(v.y, m, 64);
  return r;
}
// acc += u*v (complex)
__device__ __forceinline__ float2 cfma(float2 u, float2 v, float2 acc) {
  acc.x = fmaf(u.x, v.x, fmaf(-u.y, v.y, acc.x));
  acc.y = fmaf(u.x, v.y, fmaf(u.y, v.x, acc.y));
  return acc;
}

// general 2x2 gate on qubit q
__device__ __forceinline__ void apply_gate(float2 (&a)[4], int q, float2 u00,
                                           float2 u01, float2 u10, float2 u11,
                                           int lane) {
  const float2 z0 = make_float2(0.f, 0.f);
  if (q == 7) {  // amp bit 0: pairs (0,1),(2,3)
    float2 n0 = cfma(u00, a[0], cfma(u01, a[1], z0));
    float2 n1 = cfma(u10, a[0], cfma(u11, a[1], z0));
    float2 n2 = cfma(u00, a[2], cfma(u01, a[3], z0));
    float2 n3 = cfma(u10, a[2], cfma(u11, a[3], z0));
    a[0] = n0; a[1] = n1; a[2] = n2; a[3] = n3;
  } else if (q == 6) {  // amp bit 1: pairs (0,2),(1,3)
    float2 n0 = cfma(u00, a[0], cfma(u01, a[2], z0));
    float2 n2 = cfma(u10, a[0], cfma(u11, a[2], z0));
    float2 n1 = cfma(u00, a[1], cfma(u01, a[3], z0));
    float2 n3 = cfma(u10, a[1], cfma(u11, a[3], z0));
    a[0] = n0; a[1] = n1; a[2] = n2; a[3] = n3;
  } else {  // lane bit (5-q)
    int m = 1 << (5 - q);
    bool b = (lane >> (5 - q)) & 1;
    float2 ca = b ? u11 : u00;
    float2 cp = b ? u10 : u01;
    #pragma unroll
    for (int k = 0; k < 4; ++k) {
      float2 p = shfl_xor_f2(a[k], m);
      a[k] = cfma(ca, a[k], cfma(cp, p, z0));
    }
  }
}

// CNOT(control q, target q+1)
__device__ __forceinline__ void apply_cnot(float2 (&a)[4], int q, int lane) {
  if (q <= 4) {
    int m = 1 << (4 - q);
    bool ctrl = (lane >> (5 - q)) & 1;
    #pragma unroll
    for (int k = 0; k < 4; ++k) {
      float2 p = shfl_xor_f2(a[k], m);
      a[k].x = ctrl ? p.x : a[k].x;
      a[k].y = ctrl ? p.y : a[k].y;
    }
  } else if (q == 5) {  // control = lane bit 0, target = k bit 1
    bool ct = lane & 1;
    float2 n0 = ct ? a[2] : a[0];
    float2 n1 = ct ? a[3] : a[1];
    float2 n2 = ct ? a[0] : a[2];
    float2 n3 = ct ? a[1] : a[3];
    a[0] = n0; a[1] = n1; a[2] = n2; a[3] = n3;
  } else {  // q == 6: control = k bit 1, target = k bit 0
    float2 t = a[2]; a[2] = a[3]; a[3] = t;
  }
}

__global__ __launch_bounds__(256) void k01_kernel(
    const float* __restrict__ x, const float* __restrict__ W_in,
    const float* __restrict__ theta, __hip_bfloat16* __restrict__ Bt,
    __hip_bfloat16* __restrict__ psi, int psi_stride, int B) {
  __shared__ float mats[32 * 8];
  const int tid = threadIdx.x;
  const int lane = tid & 63;

  if (blockIdx.x < 64) {
    // ---------------- U-build: fused gate matrices, then basis-state sim ----
    if (tid < 32) {
      int l = tid >> 3, q = tid & 7;
      const float* th = theta + (l * 8 + q) * 3;
      float h1 = 0.5f * th[0], h2 = 0.5f * th[1], h3 = 0.5f * th[2];
      float c1 = cosf(h1), s1 = sinf(h1);
      float c2 = cosf(h2), s2 = sinf(h2);
      float c3 = cosf(h3), s3 = sinf(h3);
      // M = RY*RX
      float m00r = c2 * c1, m00i = s2 * s1;
      float m01r = -s2 * c1, m01i = -c2 * s1;
      float m10r = s2 * c1, m10i = -c2 * s1;
      float m11r = c1 * c2, m11i = -s1 * s2;
      // U = RZ*M: row0 *= (c3 - i s3), row1 *= (c3 + i s3)
      float* o = &mats[tid * 8];
      o[0] = c3 * m00r + s3 * m00i;  o[1] = c3 * m00i - s3 * m00r;
      o[2] = c3 * m01r + s3 * m01i;  o[3] = c3 * m01i - s3 * m01r;
      o[4] = c3 * m10r - s3 * m10i;  o[5] = c3 * m10i + s3 * m10r;
      o[6] = c3 * m11r - s3 * m11i;  o[7] = c3 * m11i + s3 * m11r;
    }
    __syncthreads();

    const int j = blockIdx.x * 4 + (tid >> 6);  // basis column 0..255
    float2 a[4];
    #pragma unroll
    for (int k = 0; k < 4; ++k)
      a[k] = make_float2((lane * 4 + k == j) ? 1.f : 0.f, 0.f);

    #pragma unroll
    for (int l = 0; l < 4; ++l) {
      #pragma unroll
      for (int q = 0; q < 8; ++q) {
        const float* m = &mats[(l * 8 + q) * 8];
        float2 u00 = make_float2(m[0], m[1]);
        float2 u01 = make_float2(m[2], m[3]);
        float2 u10 = make_float2(m[4], m[5]);
        float2 u11 = make_float2(m[6], m[7]);
        apply_gate(a, q, u00, u01, u10, u11, lane);
      }
      #pragma unroll
      for (int i = (l & 1); i < 7; i += 2) apply_cnot(a, i, lane);
    }
    // Bt[n][j], n = 2i + c, i = lane*4 + k  (row-major 512 x 256)
    #pragma unroll
    for (int k = 0; k < 4; ++k) {
      int n0 = (lane * 4 + k) * 2;
      Bt[n0 * 256 + j]       = __float2bfloat16(a[k].x);
      Bt[(n0 + 1) * 256 + j] = __float2bfloat16(a[k].y);
    }
    return;
  }

  // ---------------- encoding + psi_in ----------------
  const int b = (int)(blockIdx.x - 64) * 4 + (tid >> 6);
  if (b >= B) return;

  float xv[8];
  #pragma unroll
  for (int j = 0; j < 8; ++j) xv[j] = x[b * 512 + j * 64 + lane];

  float acc[8];
  #pragma unroll
  for (int q = 0; q < 8; ++q) {
    float s = 0.f;
    #pragma unroll
    for (int j = 0; j < 8; ++j)
      s = fmaf(xv[j], W_in[q * 512 + j * 64 + lane], s);
    acc[q] = s;
  }
  #pragma unroll
  for (int m = 1; m < 64; m <<= 1) {
    #pragma unroll
    for (int q = 0; q < 8; ++q) acc[q] += __shfl_xor(acc[q], m, 64);
  }

  float cq[8], sq[8];
  #pragma unroll
  for (int q = 0; q < 8; ++q) {
    float e  = __expf(2.f * acc[q]);
    float th = 1.f - __fdividef(2.f, e + 1.f);  // tanh
    float h  = 0.5f * 3.14159265358979323846f * th;
    cq[q] = __cosf(h);
    sq[q] = __sinf(h);
  }

  float base = 1.f;
  #pragma unroll
  for (int q = 0; q < 6; ++q)
    base *= ((lane >> (5 - q)) & 1) ? sq[q] : cq[q];

  float a0 = base * cq[6] * cq[7];
  float a1 = base * cq[6] * sq[7];
  float a2 = base * sq[6] * cq[7];
  float a3 = base * sq[6] * sq[7];

  __hip_bfloat16 h4[4] = {__float2bfloat16(a0), __float2bfloat16(a1),
                          __float2bfloat16(a2), __float2bfloat16(a3)};
  uint2 pk = *reinterpret_cast<uint2*>(h4);
  *reinterpret_cast<uint2*>(psi + (size_t)b * psi_stride + lane * 4) = pk;
}

__global__ __launch_bounds__(256, 1) void k2_kernel(
    const __hip_bfloat16* __restrict__ psi, const __hip_bfloat16* __restrict__ Bt,
    const float* __restrict__ W_out, float* __restrict__ out, int psi_stride) {
  __shared__ float z_lds[4][32][8];
  __shared__ float z_final[32][8];
  const int tid = threadIdx.x;
  const int lane = tid & 63;
  const int w = tid >> 6;
  const int rowbase = blockIdx.x * 32;
  const int cl = lane & 15;  // col-lane
  const int kg = lane >> 4;  // k-group

  const short* psis = (const short*)psi;
  const short* Bts  = (const short*)Bt;

  // A fragments: A[row][k] = psi_in, row = rowbase + rt*16 + cl, k contiguous
  bf16x8 Af[2][8];
  #pragma unroll
  for (int rt = 0; rt < 2; ++rt)
    #pragma unroll
    for (int kb = 0; kb < 8; ++kb)
      Af[rt][kb] = *(const bf16x8*)(psis +
          (size_t)(rowbase + rt * 16 + cl) * psi_stride + kb * 32 + kg * 8);

  const int wcol = w * 128;
  f32x4 acc[2][8];
  #pragma unroll
  for (int rt = 0; rt < 2; ++rt)
    #pragma unroll
    for (int ct = 0; ct < 8; ++ct) acc[rt][ct] = (f32x4){0.f, 0.f, 0.f, 0.f};

  #pragma unroll
  for (int ct = 0; ct < 8; ++ct) {
    const short* bp = Bts + (size_t)(wcol + ct * 16 + cl) * 256 + kg * 8;
    bf16x8 Bf[8];
    #pragma unroll
    for (int kb = 0; kb < 8; ++kb) Bf[kb] = *(const bf16x8*)(bp + kb * 32);
    #pragma unroll
    for (int kb = 0; kb < 8; ++kb) {
      acc[0][ct] = __builtin_amdgcn_mfma_f32_16x16x32_bf16(Af[0][kb], Bf[kb],
                                                           acc[0][ct], 0, 0, 0);
      acc[1][ct] = __builtin_amdgcn_mfma_f32_16x16x32_bf16(Af[1][kb], Bf[kb],
                                                           acc[1][ct], 0, 0, 0);
    }
  }

  // ---- epilogue: P_i = re^2+im^2, z_q += sign * P. Even lanes do q0..3,
  // odd lanes q4..7 (partner lane holds the other component of the same i).
  float zacc[2][4][4];
  #pragma unroll
  for (int rt = 0; rt < 2; ++rt)
    #pragma unroll
    for (int u = 0; u < 4; ++u)
      #pragma unroll
      for (int jr = 0; jr < 4; ++jr) zacc[rt][u][jr] = 0.f;

  #pragma unroll
  for (int ct = 0; ct < 8; ++ct) {
    int n = wcol + ct * 16 + cl;
    int i = n >> 1;
    int ib = (lane & 1) ? (i & 15) : (i >> 4);
    float s[4];
    #pragma unroll
    for (int u = 0; u < 4; ++u)
      s[u] = ((ib >> (3 - u)) & 1) ? -1.f : 1.f;
    #pragma unroll
    for (int rt = 0; rt < 2; ++rt) {
      #pragma unroll
      for (int jr = 0; jr < 4; ++jr) {
        float v = acc[rt][ct][jr];
        v = v * v;
        float P = v + __shfl_xor(v, 1, 64);
        #pragma unroll
        for (int u = 0; u < 4; ++u)
          zacc[rt][u][jr] = fmaf(s[u], P, zacc[rt][u][jr]);
      }
    }
  }

  // reduce over same-parity col-lanes (lane bits 1..3)
  #pragma unroll
  for (int m = 2; m <= 8; m <<= 1)
    #pragma unroll
    for (int rt = 0; rt < 2; ++rt)
      #pragma unroll
      for (int u = 0; u < 4; ++u)
        #pragma unroll
        for (int jr = 0; jr < 4; ++jr)
          zacc[rt][u][jr] += __shfl_xor(zacc[rt][u][jr], m, 64);

  if (cl <= 1) {
    #pragma unroll
    for (int rt = 0; rt < 2; ++rt)
      #pragma unroll
      for (int u = 0; u < 4; ++u)
        #pragma unroll
        for (int jr = 0; jr < 4; ++jr)
          z_lds[w][rt * 16 + kg * 4 + jr][(lane & 1) * 4 + u] = zacc[rt][u][jr];
  }
  __syncthreads();

  {  // sum the 4 wave-partials
    int r = tid >> 3, q = tid & 7;
    z_final[r][q] = z_lds[0][r][q] + z_lds[1][r][q] + z_lds[2][r][q] +
                    z_lds[3][r][q];
  }
  __syncthreads();

  // ---- out = z @ W_out^T ----
  const int o0 = tid, o1 = 256 + tid;
  float4 wa0 = *(const float4*)(W_out + o0 * 8);
  float4 wb0 = *(const float4*)(W_out + o0 * 8 + 4);
  float4 wa1 = *(const float4*)(W_out + o1 * 8);
  float4 wb1 = *(const float4*)(W_out + o1 * 8 + 4);
  #pragma unroll 4
  for (int r = 0; r < 32; ++r) {
    float4 z0 = *(const float4*)&z_final[r][0];
    float4 z1 = *(const float4*)&z_final[r][4];
    float d0 = wa0.x * z0.x + wa0.y * z0.y + wa0.z * z0.z + wa0.w * z0.w +
               wb0.x * z1.x + wb0.y * z1.y + wb0.z * z1.z + wb0.w * z1.w;
    float d1 = wa1.x * z0.x + wa1.y * z0.y + wa1.z * z0.z + wa1.w * z0.w +
               wb1.x * z1.x + wb1.y * z1.y + wb1.z * z1.z + wb1.w * z1.w;
    out[(size_t)(rowbase + r) * 512 + o0] = d0;
    out[(size_t)(rowbase + r) * 512 + o1] = d1;
  }
}

extern "C" void kernel_launch(void* const* d_in, const int* in_sizes, int n_in,
                              void* d_out, int out_size, void* d_ws, size_t ws_size,
                              hipStream_t stream) {
  const float* x     = (const float*)d_in[0];  // (B, 512)
  const float* W_in  = (const float*)d_in[1];  // (8, 512)
  const float* W_out = (const float*)d_in[2];  // (512, 8)
  const float* theta = (const float*)d_in[3];  // (4, 8, 3)
  float* out = (float*)d_out;

  const int B = in_sizes[0] / 512;  // 8192
  const size_t btBytes  = 512 * 256 * sizeof(__hip_bfloat16);   // 256 KiB
  const size_t psiBytes = (size_t)B * 256 * sizeof(__hip_bfloat16);

  __hip_bfloat16* Bt = (__hip_bfloat16*)d_ws;
  __hip_bfloat16* psi;
  int psi_stride;
  if (ws_size >= btBytes + psiBytes) {
    psi = (__hip_bfloat16*)((char*)d_ws + btBytes);
    psi_stride = 256;
  } else {
    // overlay psi inside d_out: psi row b occupies the first 512 B of out
    // row b (out row = 2048 B). k2 reads its own rows before the barrier
    // that precedes its out-writes, so this is race-free.
    psi = (__hip_bfloat16*)d_out;
    psi_stride = 1024;
  }

  hipLaunchKernelGGL(k01_kernel, dim3(64 + B / 4), dim3(256), 0, stream,
                     x, W_in, theta, Bt, psi, psi_stride, B);
  hipLaunchKernelGGL(k2_kernel, dim3(B / 32), dim3(256), 0, stream,
                     psi, Bt, W_out, out, psi_stride);
}